// Round 1
// baseline (464.121 us; speedup 1.0000x reference)
//
#include <hip/hip_runtime.h>
#include <stdint.h>

#define TOK 32768      // B*S
#define H 768
#define NE 8
#define CAP 8192       // max tokens per expert per rank (expected ~4096, 68-sigma margin)
#define BM 128
#define BN 128
#define BK 32

typedef __bf16 bf16x8 __attribute__((ext_vector_type(8)));
typedef float  f32x4  __attribute__((ext_vector_type(4)));

// ws layout (bytes):
//   [0,64)                      counts[16]  (0..7 rank-0, 8..15 rank-1)
//   [256, +TOK*16)              assign[TOK] : int4 (e0, e1, bits(w0), bits(w1))
//   [OFF_L0/W0/L1/W1, NE*CAP*4 each)  per-rank per-expert token lists + weights
//   [OFF_XB, +TOK*H*2)          x in bf16
//   [OFF_WB, +NE*H*H*2)         expert_w in bf16
#define OFF_ASSIGN 256
#define OFF_L0 (OFF_ASSIGN + TOK*16)
#define OFF_W0 (OFF_L0 + NE*CAP*4)
#define OFF_L1 (OFF_W0 + NE*CAP*4)
#define OFF_W1 (OFF_L1 + NE*CAP*4)
#define OFF_XB (OFF_W1 + NE*CAP*4)
#define OFF_WB (OFF_XB + (size_t)TOK*H*2)

__device__ __forceinline__ unsigned short f2bf(float f) {
    uint32_t u = __builtin_bit_cast(uint32_t, f);
    u = (u + 0x7fffu + ((u >> 16) & 1u)) >> 16;   // RNE
    return (unsigned short)u;
}

__device__ __forceinline__ void async_cp16(const void* g, void* l) {
    __builtin_amdgcn_global_load_lds(
        (const __attribute__((address_space(1))) void*)g,
        (__attribute__((address_space(3))) void*)l, 16, 0, 0);
}

// ---------------- expert_w fp32 -> bf16 ----------------
__global__ __launch_bounds__(256) void convert_w(const float* __restrict__ src,
                                                 unsigned short* __restrict__ dst, int n4) {
    int i = blockIdx.x * 256 + threadIdx.x;
    if (i < n4) {
        float4 v = ((const float4*)src)[i];
        ushort4 h;
        h.x = f2bf(v.x); h.y = f2bf(v.y); h.z = f2bf(v.z); h.w = f2bf(v.w);
        ((ushort4*)dst)[i] = h;
    }
}

// ---------------- router: scores, softmax, top-2 -> assign[], x->bf16 (NO atomics) ----------------
__global__ __launch_bounds__(256) void router_kernel(
    const float* __restrict__ x, const float* __restrict__ rw, const float* __restrict__ rb,
    unsigned short* __restrict__ xb, int4* __restrict__ assign)
{
    int wid  = threadIdx.x >> 6;
    int lane = threadIdx.x & 63;
    int token = blockIdx.x * 4 + wid;                  // one wave per token

    const float4* xr  = (const float4*)(x + (size_t)token * H);
    const float4* rw4 = (const float4*)rw;             // [NE][192] float4

    float s[NE];
    #pragma unroll
    for (int e = 0; e < NE; e++) s[e] = 0.f;

    #pragma unroll
    for (int i = 0; i < 3; i++) {
        int p = lane + 64 * i;                         // float4 index 0..191
        float4 xv = xr[p];
        ushort4 xh;
        xh.x = f2bf(xv.x); xh.y = f2bf(xv.y); xh.z = f2bf(xv.z); xh.w = f2bf(xv.w);
        ((ushort4*)(xb + (size_t)token * H))[p] = xh;
        #pragma unroll
        for (int e = 0; e < NE; e++) {
            float4 wv = rw4[e * 192 + p];
            s[e] += xv.x * wv.x + xv.y * wv.y + xv.z * wv.z + xv.w * wv.w;
        }
    }
    #pragma unroll
    for (int e = 0; e < NE; e++) {
        float v = s[e];
        #pragma unroll
        for (int off = 32; off; off >>= 1) v += __shfl_xor(v, off, 64);
        s[e] = v + rb[e];
    }
    if (lane == 0) {
        int e0 = 0;
        #pragma unroll
        for (int e = 1; e < NE; e++) if (s[e] > s[e0]) e0 = e;   // ties -> lowest idx (np)
        int e1 = -1;
        #pragma unroll
        for (int e = 0; e < NE; e++) {
            if (e == e0) continue;
            if (e1 < 0 || s[e] > s[e1]) e1 = e;
        }
        float mx = s[e0];
        float Z = 0.f;
        #pragma unroll
        for (int e = 0; e < NE; e++) Z += __expf(s[e] - mx);
        float p0 = __expf(s[e0] - mx) / Z;
        float p1 = __expf(s[e1] - mx) / Z;
        float inv = 1.f / (p0 + p1 + 1e-9f);
        int4 a;
        a.x = e0; a.y = e1;
        a.z = __float_as_int(p0 * inv);
        a.w = __float_as_int(p1 * inv);
        assign[token] = a;
    }
}

// ---------------- scatter: per-rank per-expert compact lists, 16 global atomics/block ----------------
#define SCAT_T 1024     // tokens per block
__global__ __launch_bounds__(256) void scatter_kernel(
    const int4* __restrict__ assign, int* __restrict__ counts,
    int* __restrict__ l0, float* __restrict__ w0,
    int* __restrict__ l1, float* __restrict__ w1)
{
    __shared__ int lcnt[2 * NE];
    __shared__ int lbase[2 * NE];
    int tid = threadIdx.x;
    if (tid < 2 * NE) lcnt[tid] = 0;
    __syncthreads();

    int4 a[SCAT_T / 256];
    int  r0[SCAT_T / 256], r1[SCAT_T / 256];
    #pragma unroll
    for (int j = 0; j < SCAT_T / 256; j++) {
        int token = blockIdx.x * SCAT_T + j * 256 + tid;
        a[j] = assign[token];
        r0[j] = atomicAdd(&lcnt[a[j].x], 1);
        r1[j] = atomicAdd(&lcnt[NE + a[j].y], 1);
    }
    __syncthreads();
    if (tid < 2 * NE) lbase[tid] = atomicAdd(&counts[tid], lcnt[tid]);
    __syncthreads();

    #pragma unroll
    for (int j = 0; j < SCAT_T / 256; j++) {
        int token = blockIdx.x * SCAT_T + j * 256 + tid;
        int p0 = lbase[a[j].x] + r0[j];
        int p1 = lbase[NE + a[j].y] + r1[j];
        l0[a[j].x * CAP + p0] = token; w0[a[j].x * CAP + p0] = __int_as_float(a[j].z);
        l1[a[j].y * CAP + p1] = token; w1[a[j].y * CAP + p1] = __int_as_float(a[j].w);
    }
}

// ---------------- grouped gather-GEMM: out (=|+=) w * (x[tok] @ W_e^T + b_e) ----------------
// 2-deep pipelined (3 LDS buffers, counted vmcnt(4)) + fragment-major LDS layout
// (LDS slot order == MFMA fragment order -> contiguous 1024B ds_read per wave, conflict-free;
//  achieved by permuting the per-lane GLOBAL source address, since global_load_lds writes
//  base + lane*16 linearly).
template <bool ACCUM>
__global__ __launch_bounds__(256) void expert_gemm(
    const unsigned short* __restrict__ xb, const unsigned short* __restrict__ wb,
    const float* __restrict__ eb, const int* __restrict__ counts,
    const int* __restrict__ lists, const float* __restrict__ wlists,
    float* __restrict__ out)
{
    int e   = blockIdx.z;
    int cnt = counts[e];
    int m0  = blockIdx.x * BM;
    if (m0 >= cnt) return;
    int n0  = blockIdx.y * BN;

    __shared__ unsigned short As[3][BM * BK];   // 8 KB per buffer, fragment-major
    __shared__ unsigned short Bs[3][BN * BK];
    __shared__ int   toks[BM];
    __shared__ float wts[BM];

    int tid = threadIdx.x;
    if (tid < BM) {
        int g = m0 + tid;
        int t = 0; float w = 0.f;
        if (g < cnt) { t = lists[e * CAP + g]; w = wlists[e * CAP + g]; }
        toks[tid] = t; wts[tid] = w;
    }
    __syncthreads();

    int wid = tid >> 6, lane = tid & 63;
    int wm = wid & 1, wn = wid >> 1;
    int quad = lane >> 4, r16 = lane & 15;

    // staging: thread (wid,lane) fills LDS slot wid*64+lane (16B each).
    // slot -> (subtile st=wid, k-chunk q=lane>>4, row r=lane&15)
    int frow = wid * 16 + r16;       // tile row this thread stages (first 64-row half)
    int c8   = quad * 8;             // k element offset within the BK=32 tile

    const unsigned short* gA0 = xb + (size_t)toks[frow]      * H + c8;
    const unsigned short* gA1 = xb + (size_t)toks[64 + frow] * H + c8;
    const unsigned short* gB0 = wb + ((size_t)e * H + n0 + frow)      * H + c8;
    const unsigned short* gB1 = wb + ((size_t)e * H + n0 + 64 + frow) * H + c8;
    char* dA = (char*)&As[0][0] + wid * 1024;   // wave-uniform base; HW adds lane*16
    char* dB = (char*)&Bs[0][0] + wid * 1024;

    f32x4 acc[4][4] = {};

#define STAGE(buf, kel) do { int _bo = (buf) * 8192;      \
    async_cp16(gA0 + (kel), dA + _bo);                    \
    async_cp16(gA1 + (kel), dA + _bo + 4096);             \
    async_cp16(gB0 + (kel), dB + _bo);                    \
    async_cp16(gB1 + (kel), dB + _bo + 4096); } while (0)

    constexpr int NT = H / BK;       // 24 K-tiles
    STAGE(0, 0);
    STAGE(1, BK);
    asm volatile("s_waitcnt vmcnt(4)" ::: "memory");   // tile 0 resident, tile 1 in flight
    __builtin_amdgcn_s_barrier();

    for (int t = 0; t < NT; t++) {
        int tn = (t + 2 < NT) ? (t + 2) : (NT - 1);    // clamped dead stage at tail
        STAGE((t + 2) % 3, tn * BK);

        const unsigned short* Ac = &As[t % 3][0];
        const unsigned short* Bc = &Bs[t % 3][0];
        bf16x8 a[4], b[4];
        #pragma unroll
        for (int mi = 0; mi < 4; mi++)
            a[mi] = *(const bf16x8*)(Ac + (wm * 4 + mi) * 512 + lane * 8);
        #pragma unroll
        for (int ni = 0; ni < 4; ni++)
            b[ni] = *(const bf16x8*)(Bc + (wn * 4 + ni) * 512 + lane * 8);

        #pragma unroll
        for (int mi = 0; mi < 4; mi++)
            #pragma unroll
            for (int ni = 0; ni < 4; ni++)
                acc[mi][ni] = __builtin_amdgcn_mfma_f32_16x16x32_bf16(a[mi], b[ni], acc[mi][ni], 0, 0, 0);

        // wait for tile t+1 only (4 newest loads = tile t+2 stay in flight)
        asm volatile("s_waitcnt vmcnt(4)" ::: "memory");
        __builtin_amdgcn_s_barrier();
    }
#undef STAGE

    float bias[4];
    #pragma unroll
    for (int ni = 0; ni < 4; ni++)
        bias[ni] = eb[e * H + n0 + wn * 64 + ni * 16 + r16];

    #pragma unroll
    for (int mi = 0; mi < 4; mi++) {
        int rowb = wm * 64 + mi * 16 + quad * 4;
        #pragma unroll
        for (int r = 0; r < 4; r++) {
            int row = rowb + r;
            if (m0 + row < cnt) {                       // mask tail rows (no zero-clobber)
                float w = wts[row];
                float* orow = out + (size_t)toks[row] * H + n0 + wn * 64;
                #pragma unroll
                for (int ni = 0; ni < 4; ni++) {
                    float v = (acc[mi][ni][r] + bias[ni]) * w;
                    if (ACCUM) v += orow[ni * 16 + r16];   // rows unique within dispatch
                    orow[ni * 16 + r16] = v;
                }
            }
        }
    }
}

extern "C" void kernel_launch(void* const* d_in, const int* in_sizes, int n_in,
                              void* d_out, int out_size, void* d_ws, size_t ws_size,
                              hipStream_t stream) {
    const float* x   = (const float*)d_in[0];
    const float* rw  = (const float*)d_in[1];
    const float* rb  = (const float*)d_in[2];
    const float* ew  = (const float*)d_in[3];
    const float* ebv = (const float*)d_in[4];
    float* out = (float*)d_out;

    char* ws = (char*)d_ws;
    int*   counts = (int*)ws;
    int4*  assign = (int4*)(ws + OFF_ASSIGN);
    int*   l0     = (int*)(ws + OFF_L0);
    float* w0     = (float*)(ws + OFF_W0);
    int*   l1     = (int*)(ws + OFF_L1);
    float* w1     = (float*)(ws + OFF_W1);
    unsigned short* xb = (unsigned short*)(ws + OFF_XB);
    unsigned short* wb = (unsigned short*)(ws + OFF_WB);

    hipMemsetAsync(counts, 0, 64, stream);

    int n4 = NE * H * H / 4;
    convert_w<<<(n4 + 255) / 256, 256, 0, stream>>>(ew, wb, n4);
    router_kernel<<<TOK / 4, 256, 0, stream>>>(x, rw, rb, xb, assign);
    scatter_kernel<<<TOK / SCAT_T, 256, 0, stream>>>(assign, counts, l0, w0, l1, w1);

    dim3 grid(CAP / BM, H / BN, NE);
    expert_gemm<false><<<grid, 256, 0, stream>>>(xb, wb, ebv, counts,      l0, w0, out);
    expert_gemm<true ><<<grid, 256, 0, stream>>>(xb, wb, ebv, counts + NE, l1, w1, out);
}

// Round 4
// 377.301 us; speedup vs baseline: 1.2301x; 1.2301x over previous
//
#include <hip/hip_runtime.h>
#include <stdint.h>

#define TOK 32768      // B*S
#define H 768
#define NE 8
#define CAP 8192       // max tokens per expert per rank (expected ~4096, 68-sigma margin)
#define BM 128
#define BN 128
#define BK 32

typedef __bf16 bf16x8 __attribute__((ext_vector_type(8)));
typedef float  f32x4  __attribute__((ext_vector_type(4)));

// ws layout (bytes):
//   [0,64)                      counts[16]  (0..7 rank-0, 8..15 rank-1)
//   [256, +TOK*16)              assign[TOK] : int4 (e0, e1, bits(w0), bits(w1))
//   [OFF_L0/W0/L1/W1, NE*CAP*4 each)  per-rank per-expert token lists + weights
//   [OFF_XB, +TOK*H*2)          x in bf16
//   [OFF_WB, +NE*H*H*2)         expert_w in bf16
#define OFF_ASSIGN 256
#define OFF_L0 (OFF_ASSIGN + TOK*16)
#define OFF_W0 (OFF_L0 + NE*CAP*4)
#define OFF_L1 (OFF_W0 + NE*CAP*4)
#define OFF_W1 (OFF_L1 + NE*CAP*4)
#define OFF_XB (OFF_W1 + NE*CAP*4)
#define OFF_WB (OFF_XB + (size_t)TOK*H*2)

__device__ __forceinline__ unsigned short f2bf(float f) {
    uint32_t u = __builtin_bit_cast(uint32_t, f);
    u = (u + 0x7fffu + ((u >> 16) & 1u)) >> 16;   // RNE
    return (unsigned short)u;
}

__device__ __forceinline__ void async_cp16(const void* g, void* l) {
    __builtin_amdgcn_global_load_lds(
        (const __attribute__((address_space(1))) void*)g,
        (__attribute__((address_space(3))) void*)l, 16, 0, 0);
}

// ---------------- expert_w fp32 -> bf16 ----------------
__global__ __launch_bounds__(256) void convert_w(const float* __restrict__ src,
                                                 unsigned short* __restrict__ dst, int n4) {
    int i = blockIdx.x * 256 + threadIdx.x;
    if (i < n4) {
        float4 v = ((const float4*)src)[i];
        ushort4 h;
        h.x = f2bf(v.x); h.y = f2bf(v.y); h.z = f2bf(v.z); h.w = f2bf(v.w);
        ((ushort4*)dst)[i] = h;
    }
}

// ---------------- router: scores, softmax, top-2 -> assign[], x->bf16 (NO atomics) ----------------
__global__ __launch_bounds__(256) void router_kernel(
    const float* __restrict__ x, const float* __restrict__ rw, const float* __restrict__ rb,
    unsigned short* __restrict__ xb, int4* __restrict__ assign)
{
    int wid  = threadIdx.x >> 6;
    int lane = threadIdx.x & 63;
    int token = blockIdx.x * 4 + wid;                  // one wave per token

    const float4* xr  = (const float4*)(x + (size_t)token * H);
    const float4* rw4 = (const float4*)rw;             // [NE][192] float4

    float s[NE];
    #pragma unroll
    for (int e = 0; e < NE; e++) s[e] = 0.f;

    #pragma unroll
    for (int i = 0; i < 3; i++) {
        int p = lane + 64 * i;                         // float4 index 0..191
        float4 xv = xr[p];
        ushort4 xh;
        xh.x = f2bf(xv.x); xh.y = f2bf(xv.y); xh.z = f2bf(xv.z); xh.w = f2bf(xv.w);
        ((ushort4*)(xb + (size_t)token * H))[p] = xh;
        #pragma unroll
        for (int e = 0; e < NE; e++) {
            float4 wv = rw4[e * 192 + p];
            s[e] += xv.x * wv.x + xv.y * wv.y + xv.z * wv.z + xv.w * wv.w;
        }
    }
    #pragma unroll
    for (int e = 0; e < NE; e++) {
        float v = s[e];
        #pragma unroll
        for (int off = 32; off; off >>= 1) v += __shfl_xor(v, off, 64);
        s[e] = v + rb[e];
    }
    if (lane == 0) {
        int e0 = 0;
        #pragma unroll
        for (int e = 1; e < NE; e++) if (s[e] > s[e0]) e0 = e;   // ties -> lowest idx (np)
        int e1 = -1;
        #pragma unroll
        for (int e = 0; e < NE; e++) {
            if (e == e0) continue;
            if (e1 < 0 || s[e] > s[e1]) e1 = e;
        }
        float mx = s[e0];
        float Z = 0.f;
        #pragma unroll
        for (int e = 0; e < NE; e++) Z += __expf(s[e] - mx);
        float p0 = __expf(s[e0] - mx) / Z;
        float p1 = __expf(s[e1] - mx) / Z;
        float inv = 1.f / (p0 + p1 + 1e-9f);
        int4 a;
        a.x = e0; a.y = e1;
        a.z = __float_as_int(p0 * inv);
        a.w = __float_as_int(p1 * inv);
        assign[token] = a;
    }
}

// ---------------- scatter: per-rank per-expert compact lists, 16 global atomics/block ----------------
#define SCAT_T 1024     // tokens per block
__global__ __launch_bounds__(256) void scatter_kernel(
    const int4* __restrict__ assign, int* __restrict__ counts,
    int* __restrict__ l0, float* __restrict__ w0,
    int* __restrict__ l1, float* __restrict__ w1)
{
    __shared__ int lcnt[2 * NE];
    __shared__ int lbase[2 * NE];
    int tid = threadIdx.x;
    if (tid < 2 * NE) lcnt[tid] = 0;
    __syncthreads();

    int4 a[SCAT_T / 256];
    int  r0[SCAT_T / 256], r1[SCAT_T / 256];
    #pragma unroll
    for (int j = 0; j < SCAT_T / 256; j++) {
        int token = blockIdx.x * SCAT_T + j * 256 + tid;
        a[j] = assign[token];
        r0[j] = atomicAdd(&lcnt[a[j].x], 1);
        r1[j] = atomicAdd(&lcnt[NE + a[j].y], 1);
    }
    __syncthreads();
    if (tid < 2 * NE) lbase[tid] = atomicAdd(&counts[tid], lcnt[tid]);
    __syncthreads();

    #pragma unroll
    for (int j = 0; j < SCAT_T / 256; j++) {
        int token = blockIdx.x * SCAT_T + j * 256 + tid;
        int p0 = lbase[a[j].x] + r0[j];
        int p1 = lbase[NE + a[j].y] + r1[j];
        l0[a[j].x * CAP + p0] = token; w0[a[j].x * CAP + p0] = __int_as_float(a[j].z);
        l1[a[j].y * CAP + p1] = token; w1[a[j].y * CAP + p1] = __int_as_float(a[j].w);
    }
}

// ---------------- grouped gather-GEMM: out (=|+=) w * (x[tok] @ W_e^T + b_e) ----------------
// 2-deep pipeline (3 LDS buffers, counted vmcnt(4), one barrier/K-step) + XOR k-chunk swizzle:
// physical 16B chunk p of row r holds logical chunk p ^ f(r), f(r)=(r&3)^(r>>2).
// Write side: lane (r,p) sources global chunk p^f(r) -> 4-lane groups still cover one
// contiguous 64B row segment (coalescing preserved); LDS dest stays linear (global_load_lds).
// Read side: logical (row,quad) read at column (quad^f(row&15))*16B -> 2-way bank aliasing (free).
//
// BARRIER PINNING (round-4 fix): a raw s_barrier bracketed only from above by the vmcnt asm
// leaves the scheduler free to hoist the next iteration's ds_reads (or STAGE's global_load_lds
// writes) up across the barrier — our vmcnt only tracks OUR wave's loads, so tile regions
// staged by OTHER waves are resident only after the barrier. sched_barrier(0) on BOTH sides
// of every s_barrier forbids any instruction from crossing (rule-#18 class of bug).
#define PIN() __builtin_amdgcn_sched_barrier(0)

template <bool ACCUM>
__global__ __launch_bounds__(256) void expert_gemm(
    const unsigned short* __restrict__ xb, const unsigned short* __restrict__ wb,
    const float* __restrict__ eb, const int* __restrict__ counts,
    const int* __restrict__ lists, const float* __restrict__ wlists,
    float* __restrict__ out)
{
    int e   = blockIdx.z;
    int cnt = counts[e];
    int m0  = blockIdx.x * BM;
    if (m0 >= cnt) return;
    int n0  = blockIdx.y * BN;

    __shared__ unsigned short As[3][BM * BK];   // 8 KB per buffer, row-major [128][32]
    __shared__ unsigned short Bs[3][BN * BK];
    __shared__ int   toks[BM];
    __shared__ float wts[BM];

    int tid = threadIdx.x;
    if (tid < BM) {
        int g = m0 + tid;
        int t = 0; float w = 0.f;
        if (g < cnt) { t = lists[e * CAP + g]; w = wlists[e * CAP + g]; }
        toks[tid] = t; wts[tid] = w;
    }
    __syncthreads();

    int wid = tid >> 6, lane = tid & 63;
    int wm = wid & 1, wn = wid >> 1;
    int quad = lane >> 4, r16 = lane & 15;

    // ---- staging addresses (coalesced: 4 lanes = contiguous 64B of one row) ----
    int sr = lane >> 2;                    // row 0..15 within this wave's 16-row group
    int qp = lane & 3;                     // physical 16B chunk this lane's data lands in
    int fs = (sr & 3) ^ (sr >> 2);         // f(sr)
    int cs = ((qp ^ fs) * 8);              // logical k-element offset this lane fetches
    int srow = wid * 16 + sr;

    const unsigned short* gA0 = xb + (size_t)toks[srow]      * H + cs;
    const unsigned short* gA1 = xb + (size_t)toks[64 + srow] * H + cs;
    const unsigned short* gB0 = wb + ((size_t)e * H + n0 + srow)      * H + cs;
    const unsigned short* gB1 = wb + ((size_t)e * H + n0 + 64 + srow) * H + cs;
    char* dA = (char*)&As[0][0] + wid * 1024;   // wave-uniform base; HW adds lane*16
    char* dB = (char*)&Bs[0][0] + wid * 1024;

    // ---- swizzled read column (same involution as write side) ----
    int fr   = (r16 & 3) ^ (r16 >> 2);     // f(r16)
    int colsw = (quad ^ fr) * 8;           // element offset within the 32-elem row

    f32x4 acc[4][4] = {};

#define STAGE(buf, kel) do { int _bo = (buf) * 8192;      \
    async_cp16(gA0 + (kel), dA + _bo);                    \
    async_cp16(gA1 + (kel), dA + _bo + 4096);             \
    async_cp16(gB0 + (kel), dB + _bo);                    \
    async_cp16(gB1 + (kel), dB + _bo + 4096); } while (0)

#define COMPUTE(t) do {                                                        \
    const unsigned short* Ac = &As[(t) % 3][0];                                \
    const unsigned short* Bc = &Bs[(t) % 3][0];                                \
    bf16x8 a[4], b[4];                                                         \
    _Pragma("unroll")                                                          \
    for (int mi = 0; mi < 4; mi++)                                             \
        a[mi] = *(const bf16x8*)(Ac + (wm * 64 + mi * 16 + r16) * BK + colsw); \
    _Pragma("unroll")                                                          \
    for (int ni = 0; ni < 4; ni++)                                             \
        b[ni] = *(const bf16x8*)(Bc + (wn * 64 + ni * 16 + r16) * BK + colsw); \
    _Pragma("unroll")                                                          \
    for (int mi = 0; mi < 4; mi++)                                             \
        _Pragma("unroll")                                                      \
        for (int ni = 0; ni < 4; ni++)                                         \
            acc[mi][ni] = __builtin_amdgcn_mfma_f32_16x16x32_bf16(             \
                a[mi], b[ni], acc[mi][ni], 0, 0, 0);                           \
} while (0)

// pinned barrier: nothing may be scheduled across the wait or the barrier
#define BOUNDARY(N) do {                                      \
    asm volatile("s_waitcnt vmcnt(" #N ")" ::: "memory");     \
    PIN();                                                    \
    __builtin_amdgcn_s_barrier();                             \
    PIN();                                                    \
    asm volatile("" ::: "memory");                            \
} while (0)

    constexpr int NT = H / BK;       // 24 K-tiles
    STAGE(0, 0);
    STAGE(1, BK);
    BOUNDARY(0);                     // order-robust prologue drain (both tiles resident)

    for (int t = 0; t < NT - 2; t++) {
        STAGE((t + 2) % 3, (t + 2) * BK);
        COMPUTE(t);
        // wait for tile t+1 only; tile t+2's 4 loads stay in flight across the barrier
        BOUNDARY(4);
    }
    // t = NT-2: nothing left to stage; drain tile NT-1's 4 outstanding loads
    COMPUTE(NT - 2);
    BOUNDARY(0);
    COMPUTE(NT - 1);
#undef STAGE
#undef COMPUTE
#undef BOUNDARY

    float bias[4];
    #pragma unroll
    for (int ni = 0; ni < 4; ni++)
        bias[ni] = eb[e * H + n0 + wn * 64 + ni * 16 + r16];

    #pragma unroll
    for (int mi = 0; mi < 4; mi++) {
        int rowb = wm * 64 + mi * 16 + quad * 4;
        #pragma unroll
        for (int r = 0; r < 4; r++) {
            int row = rowb + r;
            if (m0 + row < cnt) {                       // mask tail rows (no zero-clobber)
                float w = wts[row];
                float* orow = out + (size_t)toks[row] * H + n0 + wn * 64;
                #pragma unroll
                for (int ni = 0; ni < 4; ni++) {
                    float v = (acc[mi][ni][r] + bias[ni]) * w;
                    if (ACCUM) v += orow[ni * 16 + r16];   // rows unique within dispatch
                    orow[ni * 16 + r16] = v;
                }
            }
        }
    }
}

extern "C" void kernel_launch(void* const* d_in, const int* in_sizes, int n_in,
                              void* d_out, int out_size, void* d_ws, size_t ws_size,
                              hipStream_t stream) {
    const float* x   = (const float*)d_in[0];
    const float* rw  = (const float*)d_in[1];
    const float* rb  = (const float*)d_in[2];
    const float* ew  = (const float*)d_in[3];
    const float* ebv = (const float*)d_in[4];
    float* out = (float*)d_out;

    char* ws = (char*)d_ws;
    int*   counts = (int*)ws;
    int4*  assign = (int4*)(ws + OFF_ASSIGN);
    int*   l0     = (int*)(ws + OFF_L0);
    float* w0     = (float*)(ws + OFF_W0);
    int*   l1     = (int*)(ws + OFF_L1);
    float* w1     = (float*)(ws + OFF_W1);
    unsigned short* xb = (unsigned short*)(ws + OFF_XB);
    unsigned short* wb = (unsigned short*)(ws + OFF_WB);

    hipMemsetAsync(counts, 0, 64, stream);

    int n4 = NE * H * H / 4;
    convert_w<<<(n4 + 255) / 256, 256, 0, stream>>>(ew, wb, n4);
    router_kernel<<<TOK / 4, 256, 0, stream>>>(x, rw, rb, xb, assign);
    scatter_kernel<<<TOK / SCAT_T, 256, 0, stream>>>(assign, counts, l0, w0, l1, w1);

    dim3 grid(CAP / BM, H / BN, NE);
    expert_gemm<false><<<grid, 256, 0, stream>>>(xb, wb, ebv, counts,      l0, w0, out);
    expert_gemm<true ><<<grid, 256, 0, stream>>>(xb, wb, ebv, counts + NE, l1, w1, out);
}

// Round 5
// 366.033 us; speedup vs baseline: 1.2680x; 1.0308x over previous
//
#include <hip/hip_runtime.h>
#include <stdint.h>

#define TOK 32768      // B*S
#define H 768
#define NE 8
#define CAP 8192       // max tokens per expert per rank (expected ~4096, 68-sigma margin)
#define BM 128
#define BN 128
#define BK 32

typedef __bf16 bf16x8 __attribute__((ext_vector_type(8)));
typedef float  f32x4  __attribute__((ext_vector_type(4)));

// ws layout (bytes):
//   [0,64)                      counts[16]  (0..7 rank-0, 8..15 rank-1)
//   [256, +TOK*16)              assign[TOK] : int4 (e0, e1, bits(w0), bits(w1))
//   [OFF_L0/W0/L1/W1, NE*CAP*4 each)  per-rank per-expert token lists + weights
//   [OFF_XB, +TOK*H*2)          x in bf16
//   [OFF_WB, +NE*H*H*2)         expert_w in bf16
#define OFF_ASSIGN 256
#define OFF_L0 (OFF_ASSIGN + TOK*16)
#define OFF_W0 (OFF_L0 + NE*CAP*4)
#define OFF_L1 (OFF_W0 + NE*CAP*4)
#define OFF_W1 (OFF_L1 + NE*CAP*4)
#define OFF_XB (OFF_W1 + NE*CAP*4)
#define OFF_WB (OFF_XB + (size_t)TOK*H*2)

__device__ __forceinline__ unsigned short f2bf(float f) {
    uint32_t u = __builtin_bit_cast(uint32_t, f);
    u = (u + 0x7fffu + ((u >> 16) & 1u)) >> 16;   // RNE
    return (unsigned short)u;
}

__device__ __forceinline__ void async_cp16(const void* g, void* l) {
    __builtin_amdgcn_global_load_lds(
        (const __attribute__((address_space(1))) void*)g,
        (__attribute__((address_space(3))) void*)l, 16, 0, 0);
}

// ---------------- expert_w fp32 -> bf16 ----------------
__global__ __launch_bounds__(256) void convert_w(const float* __restrict__ src,
                                                 unsigned short* __restrict__ dst, int n4) {
    int i = blockIdx.x * 256 + threadIdx.x;
    if (i < n4) {
        float4 v = ((const float4*)src)[i];
        ushort4 h;
        h.x = f2bf(v.x); h.y = f2bf(v.y); h.z = f2bf(v.z); h.w = f2bf(v.w);
        ((ushort4*)dst)[i] = h;
    }
}

// ---------------- router: scores, softmax, top-2 -> assign[], x->bf16 (NO atomics) ----------------
__global__ __launch_bounds__(256) void router_kernel(
    const float* __restrict__ x, const float* __restrict__ rw, const float* __restrict__ rb,
    unsigned short* __restrict__ xb, int4* __restrict__ assign)
{
    int wid  = threadIdx.x >> 6;
    int lane = threadIdx.x & 63;
    int token = blockIdx.x * 4 + wid;                  // one wave per token

    const float4* xr  = (const float4*)(x + (size_t)token * H);
    const float4* rw4 = (const float4*)rw;             // [NE][192] float4

    float s[NE];
    #pragma unroll
    for (int e = 0; e < NE; e++) s[e] = 0.f;

    #pragma unroll
    for (int i = 0; i < 3; i++) {
        int p = lane + 64 * i;                         // float4 index 0..191
        float4 xv = xr[p];
        ushort4 xh;
        xh.x = f2bf(xv.x); xh.y = f2bf(xv.y); xh.z = f2bf(xv.z); xh.w = f2bf(xv.w);
        ((ushort4*)(xb + (size_t)token * H))[p] = xh;
        #pragma unroll
        for (int e = 0; e < NE; e++) {
            float4 wv = rw4[e * 192 + p];
            s[e] += xv.x * wv.x + xv.y * wv.y + xv.z * wv.z + xv.w * wv.w;
        }
    }
    #pragma unroll
    for (int e = 0; e < NE; e++) {
        float v = s[e];
        #pragma unroll
        for (int off = 32; off; off >>= 1) v += __shfl_xor(v, off, 64);
        s[e] = v + rb[e];
    }
    if (lane == 0) {
        int e0 = 0;
        #pragma unroll
        for (int e = 1; e < NE; e++) if (s[e] > s[e0]) e0 = e;   // ties -> lowest idx (np)
        int e1 = -1;
        #pragma unroll
        for (int e = 0; e < NE; e++) {
            if (e == e0) continue;
            if (e1 < 0 || s[e] > s[e1]) e1 = e;
        }
        float mx = s[e0];
        float Z = 0.f;
        #pragma unroll
        for (int e = 0; e < NE; e++) Z += __expf(s[e] - mx);
        float p0 = __expf(s[e0] - mx) / Z;
        float p1 = __expf(s[e1] - mx) / Z;
        float inv = 1.f / (p0 + p1 + 1e-9f);
        int4 a;
        a.x = e0; a.y = e1;
        a.z = __float_as_int(p0 * inv);
        a.w = __float_as_int(p1 * inv);
        assign[token] = a;
    }
}

// ---------------- scatter: per-rank per-expert compact lists, 16 global atomics/block ----------------
#define SCAT_T 1024     // tokens per block
__global__ __launch_bounds__(256) void scatter_kernel(
    const int4* __restrict__ assign, int* __restrict__ counts,
    int* __restrict__ l0, float* __restrict__ w0,
    int* __restrict__ l1, float* __restrict__ w1)
{
    __shared__ int lcnt[2 * NE];
    __shared__ int lbase[2 * NE];
    int tid = threadIdx.x;
    if (tid < 2 * NE) lcnt[tid] = 0;
    __syncthreads();

    int4 a[SCAT_T / 256];
    int  r0[SCAT_T / 256], r1[SCAT_T / 256];
    #pragma unroll
    for (int j = 0; j < SCAT_T / 256; j++) {
        int token = blockIdx.x * SCAT_T + j * 256 + tid;
        a[j] = assign[token];
        r0[j] = atomicAdd(&lcnt[a[j].x], 1);
        r1[j] = atomicAdd(&lcnt[NE + a[j].y], 1);
    }
    __syncthreads();
    if (tid < 2 * NE) lbase[tid] = atomicAdd(&counts[tid], lcnt[tid]);
    __syncthreads();

    #pragma unroll
    for (int j = 0; j < SCAT_T / 256; j++) {
        int token = blockIdx.x * SCAT_T + j * 256 + tid;
        int p0 = lbase[a[j].x] + r0[j];
        int p1 = lbase[NE + a[j].y] + r1[j];
        l0[a[j].x * CAP + p0] = token; w0[a[j].x * CAP + p0] = __int_as_float(a[j].z);
        l1[a[j].y * CAP + p1] = token; w1[a[j].y * CAP + p1] = __int_as_float(a[j].w);
    }
}

// ---------------- grouped gather-GEMM: out (=|+=) w * (x[tok] @ W_e^T + b_e) ----------------
// 2-deep pipeline (3 LDS buffers, counted vmcnt(4), pinned barriers) + XCD-pinned 1D grid:
//   bid = e + 8*(n + 6*m)  ->  with round-robin workgroup->XCD dispatch, all of expert e's
//   blocks land on XCD e (its 1.2MB B-slice becomes L2-resident), and the 6 n-blocks sharing
//   an m-tile's A rows are dispatch-adjacent -> co-resident -> A's 6x reuse absorbed by L2.
// (Round-4 lesson: the XOR k-chunk swizzle left SQ_LDS_BANK_CONFLICT bit-identical — the XOR
//  permutes lanes within the same per-row address set, so it was a no-op and is removed.)
#define PIN() __builtin_amdgcn_sched_barrier(0)

template <bool ACCUM>
__global__ __launch_bounds__(256) void expert_gemm(
    const unsigned short* __restrict__ xb, const unsigned short* __restrict__ wb,
    const float* __restrict__ eb, const int* __restrict__ counts,
    const int* __restrict__ lists, const float* __restrict__ wlists,
    float* __restrict__ out)
{
    int bid = blockIdx.x;
    int e   = bid & 7;                   // expert -> XCD pin (bid % 8 round-robin)
    int q   = bid >> 3;
    int n0  = (q % 6) * BN;              // n fastest within expert
    int m0  = (q / 6) * BM;
    int cnt = counts[e];
    if (m0 >= cnt) return;

    __shared__ unsigned short As[3][BM * BK];   // 8 KB per buffer, row-major [128][32]
    __shared__ unsigned short Bs[3][BN * BK];
    __shared__ int   toks[BM];
    __shared__ float wts[BM];

    int tid = threadIdx.x;
    if (tid < BM) {
        int g = m0 + tid;
        int t = 0; float w = 0.f;
        if (g < cnt) { t = lists[e * CAP + g]; w = wlists[e * CAP + g]; }
        toks[tid] = t; wts[tid] = w;
    }
    __syncthreads();

    int wid = tid >> 6, lane = tid & 63;
    int wm = wid & 1, wn = wid >> 1;
    int quad = lane >> 4, r16 = lane & 15;

    // ---- staging addresses (coalesced: 4 lanes = contiguous 64B of one row) ----
    int sr = lane >> 2;                    // row 0..15 within this wave's 16-row group
    int cs = (lane & 3) * 8;               // k-element offset of this lane's 16B chunk
    int srow = wid * 16 + sr;

    const unsigned short* gA0 = xb + (size_t)toks[srow]      * H + cs;
    const unsigned short* gA1 = xb + (size_t)toks[64 + srow] * H + cs;
    const unsigned short* gB0 = wb + ((size_t)e * H + n0 + srow)      * H + cs;
    const unsigned short* gB1 = wb + ((size_t)e * H + n0 + 64 + srow) * H + cs;
    char* dA = (char*)&As[0][0] + wid * 1024;   // wave-uniform base; HW adds lane*16
    char* dB = (char*)&Bs[0][0] + wid * 1024;

    f32x4 acc[4][4] = {};

#define STAGE(buf, kel) do { int _bo = (buf) * 8192;      \
    async_cp16(gA0 + (kel), dA + _bo);                    \
    async_cp16(gA1 + (kel), dA + _bo + 4096);             \
    async_cp16(gB0 + (kel), dB + _bo);                    \
    async_cp16(gB1 + (kel), dB + _bo + 4096); } while (0)

#define COMPUTE(t) do {                                                          \
    const unsigned short* Ac = &As[(t) % 3][0];                                  \
    const unsigned short* Bc = &Bs[(t) % 3][0];                                  \
    bf16x8 a[4], b[4];                                                           \
    _Pragma("unroll")                                                            \
    for (int mi = 0; mi < 4; mi++)                                               \
        a[mi] = *(const bf16x8*)(Ac + (wm * 64 + mi * 16 + r16) * BK + quad * 8);\
    _Pragma("unroll")                                                            \
    for (int ni = 0; ni < 4; ni++)                                               \
        b[ni] = *(const bf16x8*)(Bc + (wn * 64 + ni * 16 + r16) * BK + quad * 8);\
    _Pragma("unroll")                                                            \
    for (int mi = 0; mi < 4; mi++)                                               \
        _Pragma("unroll")                                                        \
        for (int ni = 0; ni < 4; ni++)                                           \
            acc[mi][ni] = __builtin_amdgcn_mfma_f32_16x16x32_bf16(               \
                a[mi], b[ni], acc[mi][ni], 0, 0, 0);                             \
} while (0)

// pinned barrier: nothing may be scheduled across the wait or the barrier
#define BOUNDARY(N) do {                                      \
    asm volatile("s_waitcnt vmcnt(" #N ")" ::: "memory");     \
    PIN();                                                    \
    __builtin_amdgcn_s_barrier();                             \
    PIN();                                                    \
    asm volatile("" ::: "memory");                            \
} while (0)

    constexpr int NT = H / BK;       // 24 K-tiles
    STAGE(0, 0);
    STAGE(1, BK);
    BOUNDARY(0);                     // order-robust prologue drain (both tiles resident)

    for (int t = 0; t < NT - 2; t++) {
        STAGE((t + 2) % 3, (t + 2) * BK);
        COMPUTE(t);
        // wait for tile t+1 only; tile t+2's 4 loads stay in flight across the barrier
        BOUNDARY(4);
    }
    // t = NT-2: nothing left to stage; drain tile NT-1's 4 outstanding loads
    COMPUTE(NT - 2);
    BOUNDARY(0);
    COMPUTE(NT - 1);
#undef STAGE
#undef COMPUTE
#undef BOUNDARY

    float bias[4];
    #pragma unroll
    for (int ni = 0; ni < 4; ni++)
        bias[ni] = eb[e * H + n0 + wn * 64 + ni * 16 + r16];

    #pragma unroll
    for (int mi = 0; mi < 4; mi++) {
        int rowb = wm * 64 + mi * 16 + quad * 4;
        #pragma unroll
        for (int r = 0; r < 4; r++) {
            int row = rowb + r;
            if (m0 + row < cnt) {                       // mask tail rows (no zero-clobber)
                float w = wts[row];
                float* orow = out + (size_t)toks[row] * H + n0 + wn * 64;
                #pragma unroll
                for (int ni = 0; ni < 4; ni++) {
                    float v = (acc[mi][ni][r] + bias[ni]) * w;
                    if (ACCUM) v += orow[ni * 16 + r16];   // rows unique within dispatch
                    orow[ni * 16 + r16] = v;
                }
            }
        }
    }
}

extern "C" void kernel_launch(void* const* d_in, const int* in_sizes, int n_in,
                              void* d_out, int out_size, void* d_ws, size_t ws_size,
                              hipStream_t stream) {
    const float* x   = (const float*)d_in[0];
    const float* rw  = (const float*)d_in[1];
    const float* rb  = (const float*)d_in[2];
    const float* ew  = (const float*)d_in[3];
    const float* ebv = (const float*)d_in[4];
    float* out = (float*)d_out;

    char* ws = (char*)d_ws;
    int*   counts = (int*)ws;
    int4*  assign = (int4*)(ws + OFF_ASSIGN);
    int*   l0     = (int*)(ws + OFF_L0);
    float* w0     = (float*)(ws + OFF_W0);
    int*   l1     = (int*)(ws + OFF_L1);
    float* w1     = (float*)(ws + OFF_W1);
    unsigned short* xb = (unsigned short*)(ws + OFF_XB);
    unsigned short* wb = (unsigned short*)(ws + OFF_WB);

    hipMemsetAsync(counts, 0, 64, stream);

    int n4 = NE * H * H / 4;
    convert_w<<<(n4 + 255) / 256, 256, 0, stream>>>(ew, wb, n4);
    router_kernel<<<TOK / 4, 256, 0, stream>>>(x, rw, rb, xb, assign);
    scatter_kernel<<<TOK / SCAT_T, 256, 0, stream>>>(assign, counts, l0, w0, l1, w1);

    int nblk = NE * (H / BN) * (CAP / BM);   // 8 * 6 * 64 = 3072, e = bid & 7
    expert_gemm<false><<<nblk, 256, 0, stream>>>(xb, wb, ebv, counts,      l0, w0, out);
    expert_gemm<true ><<<nblk, 256, 0, stream>>>(xb, wb, ebv, counts + NE, l1, w1, out);
}